// Round 1
// baseline (3413.104 us; speedup 1.0000x reference)
//
#include <hip/hip_runtime.h>

#define D 32

__device__ __forceinline__ float relu_f(float v) { return v > 0.f ? v : 0.f; }

// One edge handled by 8 threads, each doing a float4 chunk of the D=32 row.
// edge_attr reads are fully coalesced (1KB per wave64). x[src] gathers hit a
// 12.8MB array (L2/L3 resident). Scatter via hardware fp32 atomics (agent
// scope, relaxed — lowers to global_atomic_add_f32 on gfx950).
__global__ void __launch_bounds__(256) gine_scatter_kernel(
    const float* __restrict__ x,
    const float* __restrict__ ea,
    const int* __restrict__ src,
    const int* __restrict__ dst,
    float* __restrict__ aggr,
    int E)
{
    int i = blockIdx.x * blockDim.x + threadIdx.x;
    int total = E * 8;
    if (i >= total) return;
    int e = i >> 3;
    int q = i & 7;

    float4 a = reinterpret_cast<const float4*>(ea)[(size_t)e * 8 + q];
    int s = src[e];
    int d = dst[e];
    float4 xv = reinterpret_cast<const float4*>(x)[(size_t)s * 8 + q];

    float m0 = relu_f(xv.x + a.x);
    float m1 = relu_f(xv.y + a.y);
    float m2 = relu_f(xv.z + a.z);
    float m3 = relu_f(xv.w + a.w);

    float* base = aggr + (size_t)d * D + (size_t)q * 4;
    __hip_atomic_fetch_add(base + 0, m0, __ATOMIC_RELAXED, __HIP_MEMORY_SCOPE_AGENT);
    __hip_atomic_fetch_add(base + 1, m1, __ATOMIC_RELAXED, __HIP_MEMORY_SCOPE_AGENT);
    __hip_atomic_fetch_add(base + 2, m2, __ATOMIC_RELAXED, __HIP_MEMORY_SCOPE_AGENT);
    __hip_atomic_fetch_add(base + 3, m3, __ATOMIC_RELAXED, __HIP_MEMORY_SCOPE_AGENT);
}

// 8 nodes per 256-thread block. thread t: node = blk*8 + t/32, feature j = t%32.
// h=(1+eps)*x+aggr staged in LDS; y = relu(h@W1+b1)@W2+b2; out = relu(y).
// W[k*32+j]: lane j always bank j (conflict-free). h broadcast per node-group;
// two node-groups per wave → 2-way (free).
__global__ void __launch_bounds__(256) gine_node_kernel(
    const float* __restrict__ x,
    const float* __restrict__ aggr,
    const float* __restrict__ W1,
    const float* __restrict__ b1,
    const float* __restrict__ W2,
    const float* __restrict__ b2,
    const float* __restrict__ eps,
    int l,
    float* __restrict__ out,
    int N)
{
    __shared__ float W1s[D * D];
    __shared__ float W2s[D * D];
    __shared__ float b1s[D], b2s[D];
    __shared__ float hs[8][D];
    __shared__ float y1s[8][D];

    int t = threadIdx.x;
    for (int i = t; i < D * D; i += 256) {
        W1s[i] = W1[i];
        W2s[i] = W2[i];
    }
    if (t < D) { b1s[t] = b1[t]; b2s[t] = b2[t]; }

    float ep1 = 1.0f + eps[l];
    int local = t >> 5;         // node within block (0..7)
    int j = t & 31;             // feature index
    int node = blockIdx.x * 8 + local;

    __syncthreads();

    if (node < N) {
        float h = ep1 * x[(size_t)node * D + j] + aggr[(size_t)node * D + j];
        hs[local][j] = h;
    }
    __syncthreads();

    if (node < N) {
        float acc = b1s[j];
        const float* hrow = hs[local];
        #pragma unroll
        for (int k = 0; k < D; ++k)
            acc = fmaf(hrow[k], W1s[k * D + j], acc);
        y1s[local][j] = relu_f(acc);
    }
    __syncthreads();

    if (node < N) {
        float acc = b2s[j];
        const float* yrow = y1s[local];
        #pragma unroll
        for (int k = 0; k < D; ++k)
            acc = fmaf(yrow[k], W2s[k * D + j], acc);
        out[(size_t)node * D + j] = relu_f(acc);
    }
}

extern "C" void kernel_launch(void* const* d_in, const int* in_sizes, int n_in,
                              void* d_out, int out_size, void* d_ws, size_t ws_size,
                              hipStream_t stream) {
    const float* x_in = (const float*)d_in[0];
    const float* ea   = (const float*)d_in[1];
    const int*   ei   = (const int*)d_in[2];
    const float* W1   = (const float*)d_in[3];
    const float* b1   = (const float*)d_in[4];
    const float* W2   = (const float*)d_in[5];
    const float* b2   = (const float*)d_in[6];
    const float* eps  = (const float*)d_in[7];

    int N = in_sizes[0] / D;
    int E = in_sizes[1] / D;
    int L = in_sizes[3] / (D * D);

    const int* src = ei;          // edge_index[0] = j (message source)
    const int* dst = ei + E;      // edge_index[1] = i (message target)

    float* out  = (float*)d_out;
    float* bufA = (float*)d_ws;                    // N*D floats
    float* aggr = bufA + (size_t)N * D;            // N*D floats

    const float* cur = x_in;
    for (int l = 0; l < L; ++l) {
        // final layer must land in d_out; alternate backwards from there
        float* nxt = (((L - 1 - l) & 1) == 0) ? out : bufA;

        hipMemsetAsync(aggr, 0, (size_t)N * D * sizeof(float), stream);

        int total = E * 8;
        int sblocks = (total + 255) / 256;
        gine_scatter_kernel<<<sblocks, 256, 0, stream>>>(cur, ea, src, dst, aggr, E);

        int nblocks = (N + 7) / 8;
        gine_node_kernel<<<nblocks, 256, 0, stream>>>(
            cur, aggr,
            W1 + (size_t)l * D * D, b1 + (size_t)l * D,
            W2 + (size_t)l * D * D, b2 + (size_t)l * D,
            eps, l, out == nxt ? nxt : bufA, N);

        cur = nxt;
    }
}

// Round 2
// 716.660 us; speedup vs baseline: 4.7625x; 4.7625x over previous
//
#include <hip/hip_runtime.h>

#define D 32
#define SCAN_CHUNK 1024

__device__ __forceinline__ float relu_f(float v) { return v > 0.f ? v : 0.f; }

// ============================ preprocessing =============================
// Counting sort of edges by dst: histogram -> exclusive scan -> placement.
// Runs once per kernel_launch; reused by all 5 layers.

__global__ void __launch_bounds__(256) hist_kernel(
    const int* __restrict__ dst, int* __restrict__ deg, int E)
{
    int e = blockIdx.x * 256 + threadIdx.x;
    if (e < E) atomicAdd(&deg[dst[e]], 1);
}

// per-block (1024-element chunk) sums
__global__ void __launch_bounds__(256) scan_partial_kernel(
    const int* __restrict__ deg, int* __restrict__ part, int N)
{
    __shared__ int s[256];
    int t = threadIdx.x;
    int base = blockIdx.x * SCAN_CHUNK + t * 4;
    int sum = 0;
    #pragma unroll
    for (int i = 0; i < 4; ++i) { int idx = base + i; if (idx < N) sum += deg[idx]; }
    s[t] = sum;
    __syncthreads();
    for (int off = 128; off > 0; off >>= 1) {
        if (t < off) s[t] += s[t + off];
        __syncthreads();
    }
    if (t == 0) part[blockIdx.x] = s[0];
}

// serial exclusive scan of the (<=1024) partials — trivial size
__global__ void scan_part_exclusive_kernel(int* part, int nb)
{
    if (threadIdx.x == 0 && blockIdx.x == 0) {
        int run = 0;
        for (int i = 0; i < nb; ++i) { int v = part[i]; part[i] = run; run += v; }
    }
}

// in-place: deg[] -> exclusive prefix (row offsets)
__global__ void __launch_bounds__(256) scan_final_kernel(
    int* __restrict__ rowdeg, const int* __restrict__ part, int N)
{
    __shared__ int s[256];
    int t = threadIdx.x;
    int base = blockIdx.x * SCAN_CHUNK + t * 4;
    int d0 = 0, d1 = 0, d2 = 0, d3 = 0;
    if (base + 0 < N) d0 = rowdeg[base + 0];
    if (base + 1 < N) d1 = rowdeg[base + 1];
    if (base + 2 < N) d2 = rowdeg[base + 2];
    if (base + 3 < N) d3 = rowdeg[base + 3];
    int tsum = d0 + d1 + d2 + d3;
    s[t] = tsum;
    __syncthreads();
    // Hillis-Steele inclusive scan (read, sync, write, sync)
    for (int off = 1; off < 256; off <<= 1) {
        int a = (t >= off) ? s[t - off] : 0;
        __syncthreads();
        s[t] += a;
        __syncthreads();
    }
    int excl = s[t] - tsum + part[blockIdx.x];
    if (base + 0 < N) rowdeg[base + 0] = excl;
    if (base + 1 < N) rowdeg[base + 1] = excl + d0;
    if (base + 2 < N) rowdeg[base + 2] = excl + d0 + d1;
    if (base + 3 < N) rowdeg[base + 3] = excl + d0 + d1 + d2;
}

// FULL path: 8 threads/edge. Lane 0 claims slot via atomic on row[] (which
// destructively turns exclusive offsets into inclusive ones — the fused
// kernel exploits that: start = row[n-1], end = row[n]). edge_attr read
// coalesced, written as a scattered-but-contiguous 128B row.
__global__ void __launch_bounds__(256) place_full_kernel(
    const int* __restrict__ src, const int* __restrict__ dst,
    const float* __restrict__ ea, int* __restrict__ row,
    int* __restrict__ srcperm, float* __restrict__ eaperm, int E)
{
    int i = blockIdx.x * 256 + threadIdx.x;
    if (i >= E * 8) return;
    int e = i >> 3, q = i & 7;
    int pos = 0;
    if (q == 0) {
        pos = atomicAdd(&row[dst[e]], 1);
        srcperm[pos] = src[e];
    }
    pos = __shfl(pos, 0, 8);
    float4 v = reinterpret_cast<const float4*>(ea)[(size_t)e * 8 + q];
    reinterpret_cast<float4*>(eaperm)[(size_t)pos * 8 + q] = v;
}

// CSR path (ws too small for eaperm): just record the permutation
__global__ void __launch_bounds__(256) place_csr_kernel(
    const int* __restrict__ src, const int* __restrict__ dst,
    int* __restrict__ row, int* __restrict__ srcperm,
    int* __restrict__ eperm, int E)
{
    int e = blockIdx.x * 256 + threadIdx.x;
    if (e < E) {
        int pos = atomicAdd(&row[dst[e]], 1);
        srcperm[pos] = src[e];
        eperm[pos] = e;
    }
}

// ============================ fused layer ==============================
// Block = 256 thr = 8 nodes; each node owned by a 32-lane half-wave
// (g = t>>5, feature j = t&31). Edge loop: eaperm rows are sequential
// (coalesced 128B), x[src] rows gather from L2/L3. MLP fully in-register
// via width-32 shuffle broadcast; W1/W2 in LDS (lane j -> bank j,
// conflict-free; cross-half broadcast is 2-way = free).
template <int USE_PERM>
__global__ void __launch_bounds__(256) gine_fused_kernel(
    const float* __restrict__ x, const float* __restrict__ ea,
    const int* __restrict__ srcperm, const int* __restrict__ eperm,
    const int* __restrict__ row,
    const float* __restrict__ W1, const float* __restrict__ b1,
    const float* __restrict__ W2, const float* __restrict__ b2,
    const float* __restrict__ eps, int l, float* __restrict__ out, int N)
{
    __shared__ float W1s[D * D], W2s[D * D], b1s[D], b2s[D];
    int t = threadIdx.x;
    for (int i = t; i < D * D; i += 256) { W1s[i] = W1[i]; W2s[i] = W2[i]; }
    if (t < D) { b1s[t] = b1[t]; b2s[t] = b2[t]; }
    __syncthreads();   // last barrier — safe to early-out after this

    int g = t >> 5, j = t & 31;
    int node = blockIdx.x * 8 + g;
    if (node >= N) return;

    int start = node ? row[node - 1] : 0;
    int end = row[node];

    float acc = 0.f;
    int k = start;
    for (; k + 2 <= end; k += 2) {
        int s0 = srcperm[k], s1 = srcperm[k + 1];
        float e0 = USE_PERM ? ea[(size_t)k * D + j]
                            : ea[(size_t)eperm[k] * D + j];
        float e1 = USE_PERM ? ea[(size_t)(k + 1) * D + j]
                            : ea[(size_t)eperm[k + 1] * D + j];
        float x0 = x[(size_t)s0 * D + j];
        float x1 = x[(size_t)s1 * D + j];
        acc += relu_f(x0 + e0);
        acc += relu_f(x1 + e1);
    }
    if (k < end) {
        int s0 = srcperm[k];
        float e0 = USE_PERM ? ea[(size_t)k * D + j]
                            : ea[(size_t)eperm[k] * D + j];
        acc += relu_f(x[(size_t)s0 * D + j] + e0);
    }

    float h = (1.0f + eps[l]) * x[(size_t)node * D + j] + acc;

    float a1 = b1s[j];
    #pragma unroll
    for (int kk = 0; kk < D; ++kk)
        a1 = fmaf(__shfl(h, kk, 32), W1s[kk * D + j], a1);
    float y = relu_f(a1);

    float a2 = b2s[j];
    #pragma unroll
    for (int kk = 0; kk < D; ++kk)
        a2 = fmaf(__shfl(y, kk, 32), W2s[kk * D + j], a2);

    out[(size_t)node * D + j] = relu_f(a2);
}

// ===================== round-1 atomic fallback path ====================
__global__ void __launch_bounds__(256) gine_scatter_kernel(
    const float* __restrict__ x, const float* __restrict__ ea,
    const int* __restrict__ src, const int* __restrict__ dst,
    float* __restrict__ aggr, int E)
{
    int i = blockIdx.x * blockDim.x + threadIdx.x;
    if (i >= E * 8) return;
    int e = i >> 3, q = i & 7;
    float4 a = reinterpret_cast<const float4*>(ea)[(size_t)e * 8 + q];
    int s = src[e], d = dst[e];
    float4 xv = reinterpret_cast<const float4*>(x)[(size_t)s * 8 + q];
    float* base = aggr + (size_t)d * D + (size_t)q * 4;
    __hip_atomic_fetch_add(base + 0, relu_f(xv.x + a.x), __ATOMIC_RELAXED, __HIP_MEMORY_SCOPE_AGENT);
    __hip_atomic_fetch_add(base + 1, relu_f(xv.y + a.y), __ATOMIC_RELAXED, __HIP_MEMORY_SCOPE_AGENT);
    __hip_atomic_fetch_add(base + 2, relu_f(xv.z + a.z), __ATOMIC_RELAXED, __HIP_MEMORY_SCOPE_AGENT);
    __hip_atomic_fetch_add(base + 3, relu_f(xv.w + a.w), __ATOMIC_RELAXED, __HIP_MEMORY_SCOPE_AGENT);
}

__global__ void __launch_bounds__(256) gine_node_kernel(
    const float* __restrict__ x, const float* __restrict__ aggr,
    const float* __restrict__ W1, const float* __restrict__ b1,
    const float* __restrict__ W2, const float* __restrict__ b2,
    const float* __restrict__ eps, int l, float* __restrict__ out, int N)
{
    __shared__ float W1s[D * D], W2s[D * D], b1s[D], b2s[D];
    __shared__ float hs[8][D], y1s[8][D];
    int t = threadIdx.x;
    for (int i = t; i < D * D; i += 256) { W1s[i] = W1[i]; W2s[i] = W2[i]; }
    if (t < D) { b1s[t] = b1[t]; b2s[t] = b2[t]; }
    float ep1 = 1.0f + eps[l];
    int local = t >> 5, j = t & 31;
    int node = blockIdx.x * 8 + local;
    __syncthreads();
    if (node < N)
        hs[local][j] = ep1 * x[(size_t)node * D + j] + aggr[(size_t)node * D + j];
    __syncthreads();
    if (node < N) {
        float acc = b1s[j];
        #pragma unroll
        for (int k = 0; k < D; ++k) acc = fmaf(hs[local][k], W1s[k * D + j], acc);
        y1s[local][j] = relu_f(acc);
    }
    __syncthreads();
    if (node < N) {
        float acc = b2s[j];
        #pragma unroll
        for (int k = 0; k < D; ++k) acc = fmaf(y1s[local][k], W2s[k * D + j], acc);
        out[(size_t)node * D + j] = relu_f(acc);
    }
}

// ============================== launcher ===============================
extern "C" void kernel_launch(void* const* d_in, const int* in_sizes, int n_in,
                              void* d_out, int out_size, void* d_ws, size_t ws_size,
                              hipStream_t stream) {
    const float* x_in = (const float*)d_in[0];
    const float* ea   = (const float*)d_in[1];
    const int*   ei   = (const int*)d_in[2];
    const float* W1   = (const float*)d_in[3];
    const float* b1   = (const float*)d_in[4];
    const float* W2   = (const float*)d_in[5];
    const float* b2   = (const float*)d_in[6];
    const float* eps  = (const float*)d_in[7];

    int N = in_sizes[0] / D;
    int E = in_sizes[1] / D;
    int L = in_sizes[3] / (D * D);

    const int* src = ei;       // edge_index[0] = message source j
    const int* dst = ei + E;   // edge_index[1] = message target i

    float* out = (float*)d_out;
    char*  ws  = (char*)d_ws;

    // ---- workspace layout (256B aligned) ----
    size_t off = 0;
    auto take = [&](size_t bytes) -> size_t {
        size_t p = off; off = (off + bytes + 255) & ~(size_t)255; return p;
    };
    size_t o_bufA    = take((size_t)N * D * sizeof(float));
    size_t o_row     = take((size_t)(N + 8) * sizeof(int));
    size_t o_part    = take(1024 * sizeof(int));
    size_t o_srcperm = take((size_t)E * sizeof(int));
    size_t base_need = off;
    size_t o_eperm   = base_need;                         // CSR path
    size_t need_csr  = base_need + (((size_t)E * sizeof(int) + 255) & ~(size_t)255);
    size_t o_eaperm  = base_need;                         // FULL path
    size_t need_full = base_need + (size_t)E * D * sizeof(float);

    float* bufA    = (float*)(ws + o_bufA);
    int*   row     = (int*)(ws + o_row);
    int*   part    = (int*)(ws + o_part);
    int*   srcperm = (int*)(ws + o_srcperm);

    int path = (ws_size >= need_full) ? 2 : (ws_size >= need_csr ? 1 : 0);

    if (path == 0) {
        // ---- atomic fallback (round-1) ----
        float* aggr = bufA + (size_t)N * D;
        const float* cur = x_in;
        for (int l = 0; l < L; ++l) {
            float* nxt = (((L - 1 - l) & 1) == 0) ? out : bufA;
            hipMemsetAsync(aggr, 0, (size_t)N * D * sizeof(float), stream);
            gine_scatter_kernel<<<(E * 8 + 255) / 256, 256, 0, stream>>>(cur, ea, src, dst, aggr, E);
            gine_node_kernel<<<(N + 7) / 8, 256, 0, stream>>>(
                cur, aggr, W1 + (size_t)l * D * D, b1 + (size_t)l * D,
                W2 + (size_t)l * D * D, b2 + (size_t)l * D, eps, l, nxt, N);
            cur = nxt;
        }
        return;
    }

    int*   eperm  = (int*)(ws + o_eperm);
    float* eaperm = (float*)(ws + o_eaperm);

    // ---- preprocessing (once per call) ----
    int nb = (N + SCAN_CHUNK - 1) / SCAN_CHUNK;   // 98 for N=100k (<=1024)
    hipMemsetAsync(row, 0, (size_t)N * sizeof(int), stream);
    hist_kernel<<<(E + 255) / 256, 256, 0, stream>>>(dst, row, E);
    scan_partial_kernel<<<nb, 256, 0, stream>>>(row, part, N);
    scan_part_exclusive_kernel<<<1, 64, 0, stream>>>(part, nb);
    scan_final_kernel<<<nb, 256, 0, stream>>>(row, part, N);
    if (path == 2) {
        place_full_kernel<<<(E * 8 + 255) / 256, 256, 0, stream>>>(
            src, dst, ea, row, srcperm, eaperm, E);
    } else {
        place_csr_kernel<<<(E + 255) / 256, 256, 0, stream>>>(
            src, dst, row, srcperm, eperm, E);
    }
    // row[n] is now the INCLUSIVE prefix (end offset of node n)

    // ---- 5 fused layers ----
    const float* cur = x_in;
    for (int l = 0; l < L; ++l) {
        float* nxt = (((L - 1 - l) & 1) == 0) ? out : bufA;
        if (path == 2) {
            gine_fused_kernel<1><<<(N + 7) / 8, 256, 0, stream>>>(
                cur, eaperm, srcperm, eperm, row,
                W1 + (size_t)l * D * D, b1 + (size_t)l * D,
                W2 + (size_t)l * D * D, b2 + (size_t)l * D, eps, l, nxt, N);
        } else {
            gine_fused_kernel<0><<<(N + 7) / 8, 256, 0, stream>>>(
                cur, ea, srcperm, eperm, row,
                W1 + (size_t)l * D * D, b1 + (size_t)l * D,
                W2 + (size_t)l * D * D, b2 + (size_t)l * D, eps, l, nxt, N);
        }
        cur = nxt;
    }
}

// Round 3
// 631.911 us; speedup vs baseline: 5.4012x; 1.1341x over previous
//
#include <hip/hip_runtime.h>

#define D 32
#define NPB 64                      // nodes per fused block (ldst fits 6 bits)
#define SRC_BITS 25
#define SRC_MASK ((1 << SRC_BITS) - 1)
#define SCAN_CHUNK 1024

__device__ __forceinline__ float relu_f(float v) { return v > 0.f ? v : 0.f; }

// ============================ preprocessing =============================
__global__ void __launch_bounds__(256) hist_kernel(
    const int* __restrict__ dst, int* __restrict__ deg, int E)
{
    int e = blockIdx.x * 256 + threadIdx.x;
    if (e < E) atomicAdd(&deg[dst[e]], 1);
}

__global__ void __launch_bounds__(256) scan_partial_kernel(
    const int* __restrict__ deg, int* __restrict__ part, int N)
{
    __shared__ int s[256];
    int t = threadIdx.x;
    int base = blockIdx.x * SCAN_CHUNK + t * 4;
    int sum = 0;
    #pragma unroll
    for (int i = 0; i < 4; ++i) { int idx = base + i; if (idx < N) sum += deg[idx]; }
    s[t] = sum;
    __syncthreads();
    for (int off = 128; off > 0; off >>= 1) {
        if (t < off) s[t] += s[t + off];
        __syncthreads();
    }
    if (t == 0) part[blockIdx.x] = s[0];
}

__global__ void scan_part_exclusive_kernel(int* part, int nb)
{
    if (threadIdx.x == 0 && blockIdx.x == 0) {
        int run = 0;
        for (int i = 0; i < nb; ++i) { int v = part[i]; part[i] = run; run += v; }
    }
}

__global__ void __launch_bounds__(256) scan_final_kernel(
    int* __restrict__ rowdeg, const int* __restrict__ part, int N)
{
    __shared__ int s[256];
    int t = threadIdx.x;
    int base = blockIdx.x * SCAN_CHUNK + t * 4;
    int d0 = 0, d1 = 0, d2 = 0, d3 = 0;
    if (base + 0 < N) d0 = rowdeg[base + 0];
    if (base + 1 < N) d1 = rowdeg[base + 1];
    if (base + 2 < N) d2 = rowdeg[base + 2];
    if (base + 3 < N) d3 = rowdeg[base + 3];
    int tsum = d0 + d1 + d2 + d3;
    s[t] = tsum;
    __syncthreads();
    for (int off = 1; off < 256; off <<= 1) {
        int a = (t >= off) ? s[t - off] : 0;
        __syncthreads();
        s[t] += a;
        __syncthreads();
    }
    int excl = s[t] - tsum + part[blockIdx.x];
    if (base + 0 < N) rowdeg[base + 0] = excl;
    if (base + 1 < N) rowdeg[base + 1] = excl + d0;
    if (base + 2 < N) rowdeg[base + 2] = excl + d0 + d1;
    if (base + 3 < N) rowdeg[base + 3] = excl + d0 + d1 + d2;
}

// FULL path: 8 threads/edge. Lane 0 claims slot (turning row[] exclusive ->
// inclusive, which the fused kernel exploits) and writes the PACKED index
// src | (dst&(NPB-1))<<SRC_BITS. edge_attr row copied to its sorted slot.
__global__ void __launch_bounds__(256) place_full_kernel(
    const int* __restrict__ src, const int* __restrict__ dst,
    const float* __restrict__ ea, int* __restrict__ row,
    int* __restrict__ srcpk, float* __restrict__ eaperm, int E)
{
    int i = blockIdx.x * 256 + threadIdx.x;
    if (i >= E * 8) return;
    int e = i >> 3, q = i & 7;
    int pos = 0;
    if (q == 0) {
        int d = dst[e];
        pos = atomicAdd(&row[d], 1);
        srcpk[pos] = src[e] | ((d & (NPB - 1)) << SRC_BITS);
    }
    pos = __shfl(pos, 0, 8);
    float4 v = reinterpret_cast<const float4*>(ea)[(size_t)e * 8 + q];
    reinterpret_cast<float4*>(eaperm)[(size_t)pos * 8 + q] = v;
}

// CSR fallback path: plain permutation record
__global__ void __launch_bounds__(256) place_csr_kernel(
    const int* __restrict__ src, const int* __restrict__ dst,
    int* __restrict__ row, int* __restrict__ srcperm,
    int* __restrict__ eperm, int E)
{
    int e = blockIdx.x * 256 + threadIdx.x;
    if (e < E) {
        int pos = atomicAdd(&row[dst[e]], 1);
        srcperm[pos] = src[e];
        eperm[pos] = e;
    }
}

// ========================= fused layer (v2) ============================
// Block = 256 thr = 8 half-waves, owns NPB=64 consecutive nodes and their
// contiguous dst-sorted edge range. Each half-wave: contiguous edge chunk,
// segmented register accumulation (flush to LDS aggr via ds_add_f32 on dst
// change, ~1 per 16 edges). Packed indices batch-loaded 32-at-a-time and
// shfl-broadcast, so ea (stream) + x (128B-line gather) loads are all
// independent -> deep pipeline. MLP phase in-block after barrier.
__global__ void __launch_bounds__(256) gine_fused2_kernel(
    const float* __restrict__ x, const float* __restrict__ eaperm,
    const int* __restrict__ srcpk, const int* __restrict__ row,
    const float* __restrict__ W1, const float* __restrict__ b1,
    const float* __restrict__ W2, const float* __restrict__ b2,
    const float* __restrict__ eps, int l, float* __restrict__ out, int N)
{
    __shared__ float aggr[NPB][D];          // 8KB: lane j -> bank j
    __shared__ float W1s[D * D], W2s[D * D];
    __shared__ float b1s[D], b2s[D];
    __shared__ float ys[8][D];

    int t = threadIdx.x;
    for (int i = t; i < D * D; i += 256) { W1s[i] = W1[i]; W2s[i] = W2[i]; }
    if (t < D) { b1s[t] = b1[t]; b2s[t] = b2[t]; }
    for (int i = t; i < NPB * D; i += 256) ((float*)aggr)[i] = 0.f;

    int hw = t >> 5;                        // half-wave 0..7
    int j  = t & 31;                        // feature
    int n0 = blockIdx.x * NPB;
    int nlast = min(n0 + NPB - 1, N - 1);
    int estart = n0 ? row[n0 - 1] : 0;      // row[] is inclusive prefix
    int eend   = row[nlast];
    __syncthreads();

    // -------- edge aggregation --------
    int EB = eend - estart;
    int chunk = (EB + 7) >> 3;
    int a = estart + hw * chunk;
    int b = min(a + chunk, eend);

    float acc = 0.f;
    int cur = -1;
    int k = a;
    while (k < b) {
        int rem = b - k;
        if (rem >= 32) {
            int pv = srcpk[k + j];          // 32 packed indices, one coalesced load
            #pragma unroll 8
            for (int i = 0; i < 32; ++i) {
                int p  = __shfl(pv, i, 32);
                int s  = p & SRC_MASK;
                int ld = p >> SRC_BITS;
                float ev = eaperm[(size_t)(k + i) * D + j];
                float xv = x[(size_t)s * D + j];
                if (ld != cur) {
                    if (cur >= 0) atomicAdd(&aggr[cur][j], acc);
                    cur = ld; acc = 0.f;
                }
                acc += relu_f(xv + ev);
            }
            k += 32;
        } else {
            int pv = (j < rem) ? srcpk[k + j] : 0;
            for (int i = 0; i < rem; ++i) {
                int p  = __shfl(pv, i, 32);
                int s  = p & SRC_MASK;
                int ld = p >> SRC_BITS;
                float ev = eaperm[(size_t)(k + i) * D + j];
                float xv = x[(size_t)s * D + j];
                if (ld != cur) {
                    if (cur >= 0) atomicAdd(&aggr[cur][j], acc);
                    cur = ld; acc = 0.f;
                }
                acc += relu_f(xv + ev);
            }
            k += rem;
        }
    }
    if (cur >= 0) atomicAdd(&aggr[cur][j], acc);
    __syncthreads();

    // -------- MLP: half-wave hw owns nodes hw*8 .. hw*8+7 --------
    float ep1 = 1.0f + eps[l];
    for (int r = 0; r < 8; ++r) {
        int ln = hw * 8 + r;
        int n = n0 + ln;
        if (n >= N) break;                  // no barriers below: safe
        float h = ep1 * x[(size_t)n * D + j] + aggr[ln][j];
        aggr[ln][j] = h;                    // stage for broadcast reads
        float a1 = b1s[j];
        #pragma unroll
        for (int kk = 0; kk < D; ++kk)
            a1 = fmaf(aggr[ln][kk], W1s[kk * D + j], a1);
        float y = relu_f(a1);
        ys[hw][j] = y;
        float a2 = b2s[j];
        #pragma unroll
        for (int kk = 0; kk < D; ++kk)
            a2 = fmaf(ys[hw][kk], W2s[kk * D + j], a2);
        out[(size_t)n * D + j] = relu_f(a2);
    }
}

// ================= fallback fused kernel (CSR gather path) =============
__global__ void __launch_bounds__(256) gine_fused_kernel(
    const float* __restrict__ x, const float* __restrict__ ea,
    const int* __restrict__ srcperm, const int* __restrict__ eperm,
    const int* __restrict__ row,
    const float* __restrict__ W1, const float* __restrict__ b1,
    const float* __restrict__ W2, const float* __restrict__ b2,
    const float* __restrict__ eps, int l, float* __restrict__ out, int N)
{
    __shared__ float W1s[D * D], W2s[D * D], b1s[D], b2s[D];
    int t = threadIdx.x;
    for (int i = t; i < D * D; i += 256) { W1s[i] = W1[i]; W2s[i] = W2[i]; }
    if (t < D) { b1s[t] = b1[t]; b2s[t] = b2[t]; }
    __syncthreads();

    int g = t >> 5, j = t & 31;
    int node = blockIdx.x * 8 + g;
    if (node >= N) return;
    int start = node ? row[node - 1] : 0;
    int end = row[node];

    float acc = 0.f;
    for (int k = start; k < end; ++k) {
        int s0 = srcperm[k];
        float e0 = ea[(size_t)eperm[k] * D + j];
        acc += relu_f(x[(size_t)s0 * D + j] + e0);
    }
    float h = (1.0f + eps[l]) * x[(size_t)node * D + j] + acc;
    float a1 = b1s[j];
    #pragma unroll
    for (int kk = 0; kk < D; ++kk)
        a1 = fmaf(__shfl(h, kk, 32), W1s[kk * D + j], a1);
    float y = relu_f(a1);
    float a2 = b2s[j];
    #pragma unroll
    for (int kk = 0; kk < D; ++kk)
        a2 = fmaf(__shfl(y, kk, 32), W2s[kk * D + j], a2);
    out[(size_t)node * D + j] = relu_f(a2);
}

// ===================== atomic fallback path ====================
__global__ void __launch_bounds__(256) gine_scatter_kernel(
    const float* __restrict__ x, const float* __restrict__ ea,
    const int* __restrict__ src, const int* __restrict__ dst,
    float* __restrict__ aggr, int E)
{
    int i = blockIdx.x * blockDim.x + threadIdx.x;
    if (i >= E * 8) return;
    int e = i >> 3, q = i & 7;
    float4 a = reinterpret_cast<const float4*>(ea)[(size_t)e * 8 + q];
    int s = src[e], d = dst[e];
    float4 xv = reinterpret_cast<const float4*>(x)[(size_t)s * 8 + q];
    float* base = aggr + (size_t)d * D + (size_t)q * 4;
    __hip_atomic_fetch_add(base + 0, relu_f(xv.x + a.x), __ATOMIC_RELAXED, __HIP_MEMORY_SCOPE_AGENT);
    __hip_atomic_fetch_add(base + 1, relu_f(xv.y + a.y), __ATOMIC_RELAXED, __HIP_MEMORY_SCOPE_AGENT);
    __hip_atomic_fetch_add(base + 2, relu_f(xv.z + a.z), __ATOMIC_RELAXED, __HIP_MEMORY_SCOPE_AGENT);
    __hip_atomic_fetch_add(base + 3, relu_f(xv.w + a.w), __ATOMIC_RELAXED, __HIP_MEMORY_SCOPE_AGENT);
}

__global__ void __launch_bounds__(256) gine_node_kernel(
    const float* __restrict__ x, const float* __restrict__ aggr,
    const float* __restrict__ W1, const float* __restrict__ b1,
    const float* __restrict__ W2, const float* __restrict__ b2,
    const float* __restrict__ eps, int l, float* __restrict__ out, int N)
{
    __shared__ float W1s[D * D], W2s[D * D], b1s[D], b2s[D];
    __shared__ float hs[8][D], y1s[8][D];
    int t = threadIdx.x;
    for (int i = t; i < D * D; i += 256) { W1s[i] = W1[i]; W2s[i] = W2[i]; }
    if (t < D) { b1s[t] = b1[t]; b2s[t] = b2[t]; }
    float ep1 = 1.0f + eps[l];
    int local = t >> 5, j = t & 31;
    int node = blockIdx.x * 8 + local;
    __syncthreads();
    if (node < N)
        hs[local][j] = ep1 * x[(size_t)node * D + j] + aggr[(size_t)node * D + j];
    __syncthreads();
    if (node < N) {
        float acc = b1s[j];
        #pragma unroll
        for (int k = 0; k < D; ++k) acc = fmaf(hs[local][k], W1s[k * D + j], acc);
        y1s[local][j] = relu_f(acc);
    }
    __syncthreads();
    if (node < N) {
        float acc = b2s[j];
        #pragma unroll
        for (int k = 0; k < D; ++k) acc = fmaf(y1s[local][k], W2s[k * D + j], acc);
        out[(size_t)node * D + j] = relu_f(acc);
    }
}

// ============================== launcher ===============================
extern "C" void kernel_launch(void* const* d_in, const int* in_sizes, int n_in,
                              void* d_out, int out_size, void* d_ws, size_t ws_size,
                              hipStream_t stream) {
    const float* x_in = (const float*)d_in[0];
    const float* ea   = (const float*)d_in[1];
    const int*   ei   = (const int*)d_in[2];
    const float* W1   = (const float*)d_in[3];
    const float* b1   = (const float*)d_in[4];
    const float* W2   = (const float*)d_in[5];
    const float* b2   = (const float*)d_in[6];
    const float* eps  = (const float*)d_in[7];

    int N = in_sizes[0] / D;
    int E = in_sizes[1] / D;
    int L = in_sizes[3] / (D * D);

    const int* src = ei;       // edge_index[0] = message source j
    const int* dst = ei + E;   // edge_index[1] = message target i

    float* out = (float*)d_out;
    char*  ws  = (char*)d_ws;

    size_t off = 0;
    auto take = [&](size_t bytes) -> size_t {
        size_t p = off; off = (off + bytes + 255) & ~(size_t)255; return p;
    };
    size_t o_bufA    = take((size_t)N * D * sizeof(float));
    size_t o_row     = take((size_t)(N + 8) * sizeof(int));
    size_t o_part    = take(1024 * sizeof(int));
    size_t o_srcpk   = take((size_t)E * sizeof(int));
    size_t base_need = off;
    size_t o_eperm   = base_need;                          // CSR path
    size_t need_csr  = base_need + (((size_t)E * sizeof(int) + 255) & ~(size_t)255);
    size_t o_eaperm  = base_need;                          // FULL path
    size_t need_full = base_need + (size_t)E * D * sizeof(float);

    float* bufA  = (float*)(ws + o_bufA);
    int*   row   = (int*)(ws + o_row);
    int*   part  = (int*)(ws + o_part);
    int*   srcpk = (int*)(ws + o_srcpk);

    int path = (ws_size >= need_full) ? 2 : (ws_size >= need_csr ? 1 : 0);

    if (path == 0) {
        float* aggr = bufA + (size_t)N * D;   // NOTE: requires 2*N*D ws; legacy path
        const float* cur = x_in;
        for (int l = 0; l < L; ++l) {
            float* nxt = (((L - 1 - l) & 1) == 0) ? out : bufA;
            hipMemsetAsync(aggr, 0, (size_t)N * D * sizeof(float), stream);
            gine_scatter_kernel<<<(E * 8 + 255) / 256, 256, 0, stream>>>(cur, ea, src, dst, aggr, E);
            gine_node_kernel<<<(N + 7) / 8, 256, 0, stream>>>(
                cur, aggr, W1 + (size_t)l * D * D, b1 + (size_t)l * D,
                W2 + (size_t)l * D * D, b2 + (size_t)l * D, eps, l, nxt, N);
            cur = nxt;
        }
        return;
    }

    int*   eperm  = (int*)(ws + o_eperm);
    float* eaperm = (float*)(ws + o_eaperm);

    // ---- preprocessing (once per call) ----
    int nb = (N + SCAN_CHUNK - 1) / SCAN_CHUNK;
    hipMemsetAsync(row, 0, (size_t)N * sizeof(int), stream);
    hist_kernel<<<(E + 255) / 256, 256, 0, stream>>>(dst, row, E);
    scan_partial_kernel<<<nb, 256, 0, stream>>>(row, part, N);
    scan_part_exclusive_kernel<<<1, 64, 0, stream>>>(part, nb);
    scan_final_kernel<<<nb, 256, 0, stream>>>(row, part, N);
    if (path == 2) {
        place_full_kernel<<<(E * 8 + 255) / 256, 256, 0, stream>>>(
            src, dst, ea, row, srcpk, eaperm, E);
    } else {
        place_csr_kernel<<<(E + 255) / 256, 256, 0, stream>>>(
            src, dst, row, srcpk, eperm, E);
    }
    // row[n] is now the inclusive prefix (end offset of node n)

    const float* cur = x_in;
    for (int l = 0; l < L; ++l) {
        float* nxt = (((L - 1 - l) & 1) == 0) ? out : bufA;
        if (path == 2) {
            gine_fused2_kernel<<<(N + NPB - 1) / NPB, 256, 0, stream>>>(
                cur, eaperm, srcpk, row,
                W1 + (size_t)l * D * D, b1 + (size_t)l * D,
                W2 + (size_t)l * D * D, b2 + (size_t)l * D, eps, l, nxt, N);
        } else {
            gine_fused_kernel<<<(N + 7) / 8, 256, 0, stream>>>(
                cur, ea, srcpk, eperm, row,
                W1 + (size_t)l * D * D, b1 + (size_t)l * D,
                W2 + (size_t)l * D * D, b2 + (size_t)l * D, eps, l, nxt, N);
        }
        cur = nxt;
    }
}

// Round 4
// 535.515 us; speedup vs baseline: 6.3735x; 1.1800x over previous
//
#include <hip/hip_runtime.h>

#define D 32
#define NPB 64                      // nodes per fused block (dst-local fits 6 bits)
#define SRC_BITS 25
#define SRC_MASK ((1 << SRC_BITS) - 1)
#define SCAN_CHUNK 1024

__device__ __forceinline__ float relu_f(float v) { return v > 0.f ? v : 0.f; }

// round-to-nearest-even f32 -> bf16 bits
__device__ __forceinline__ unsigned bf16_rne(float f) {
    unsigned u = __float_as_uint(f);
    return (u + 0x7FFFu + ((u >> 16) & 1u)) >> 16;
}

// ============================ preprocessing =============================
__global__ void __launch_bounds__(256) hist_kernel(
    const int* __restrict__ dst, int* __restrict__ deg, int E)
{
    int e = blockIdx.x * 256 + threadIdx.x;
    if (e < E) atomicAdd(&deg[dst[e]], 1);
}

__global__ void __launch_bounds__(256) scan_partial_kernel(
    const int* __restrict__ deg, int* __restrict__ part, int N)
{
    __shared__ int s[256];
    int t = threadIdx.x;
    int base = blockIdx.x * SCAN_CHUNK + t * 4;
    int sum = 0;
    #pragma unroll
    for (int i = 0; i < 4; ++i) { int idx = base + i; if (idx < N) sum += deg[idx]; }
    s[t] = sum;
    __syncthreads();
    for (int off = 128; off > 0; off >>= 1) {
        if (t < off) s[t] += s[t + off];
        __syncthreads();
    }
    if (t == 0) part[blockIdx.x] = s[0];
}

__global__ void scan_part_exclusive_kernel(int* part, int nb)
{
    if (threadIdx.x == 0 && blockIdx.x == 0) {
        int run = 0;
        for (int i = 0; i < nb; ++i) { int v = part[i]; part[i] = run; run += v; }
    }
}

__global__ void __launch_bounds__(256) scan_final_kernel(
    int* __restrict__ rowdeg, const int* __restrict__ part, int N)
{
    __shared__ int s[256];
    int t = threadIdx.x;
    int base = blockIdx.x * SCAN_CHUNK + t * 4;
    int d0 = 0, d1 = 0, d2 = 0, d3 = 0;
    if (base + 0 < N) d0 = rowdeg[base + 0];
    if (base + 1 < N) d1 = rowdeg[base + 1];
    if (base + 2 < N) d2 = rowdeg[base + 2];
    if (base + 3 < N) d3 = rowdeg[base + 3];
    int tsum = d0 + d1 + d2 + d3;
    s[t] = tsum;
    __syncthreads();
    for (int off = 1; off < 256; off <<= 1) {
        int a = (t >= off) ? s[t - off] : 0;
        __syncthreads();
        s[t] += a;
        __syncthreads();
    }
    int excl = s[t] - tsum + part[blockIdx.x];
    if (base + 0 < N) rowdeg[base + 0] = excl;
    if (base + 1 < N) rowdeg[base + 1] = excl + d0;
    if (base + 2 < N) rowdeg[base + 2] = excl + d0 + d1;
    if (base + 3 < N) rowdeg[base + 3] = excl + d0 + d1 + d2;
}

// FULL path: 8 threads/edge. Lane 0 claims slot (turning row[] exclusive ->
// inclusive, which the fused kernel exploits) and writes the PACKED index
// src | (dst&(NPB-1))<<SRC_BITS. edge_attr row converted to bf16 (RNE) and
// written to its dst-sorted slot (64B/row, one full line).
__global__ void __launch_bounds__(256) place_full_kernel(
    const int* __restrict__ src, const int* __restrict__ dst,
    const float* __restrict__ ea, int* __restrict__ row,
    int* __restrict__ srcpk, unsigned* __restrict__ eah, int E)
{
    int i = blockIdx.x * 256 + threadIdx.x;
    if (i >= E * 8) return;
    int e = i >> 3, q = i & 7;
    int pos = 0;
    if (q == 0) {
        int d = dst[e];
        pos = atomicAdd(&row[d], 1);
        srcpk[pos] = src[e] | ((d & (NPB - 1)) << SRC_BITS);
    }
    pos = __shfl(pos, 0, 8);
    float4 v = reinterpret_cast<const float4*>(ea)[(size_t)e * 8 + q];
    uint2 w;
    w.x = bf16_rne(v.x) | (bf16_rne(v.y) << 16);
    w.y = bf16_rne(v.z) | (bf16_rne(v.w) << 16);
    // row = 16 uints (64B); thread q writes uints 2q, 2q+1
    reinterpret_cast<uint2*>(eah)[(size_t)pos * 8 + q] = w;
}

// CSR fallback path: plain permutation record (fp32 ea gathered in layer)
__global__ void __launch_bounds__(256) place_csr_kernel(
    const int* __restrict__ src, const int* __restrict__ dst,
    int* __restrict__ row, int* __restrict__ srcperm,
    int* __restrict__ eperm, int E)
{
    int e = blockIdx.x * 256 + threadIdx.x;
    if (e < E) {
        int pos = atomicAdd(&row[dst[e]], 1);
        srcperm[pos] = src[e];
        eperm[pos] = e;
    }
}

// ========================= fused layer (v3) ============================
// Block = 256 thr = 32 groups of 8 lanes; block owns NPB=64 consecutive
// nodes + their contiguous dst-sorted edge range. Group: contiguous edge
// chunk; per edge, lane q loads uint2 (4 bf16 ea features 4q..4q+3) + one
// float4 x-gather (full 128B line per group). Segmented float4 register
// accumulation, ds_add flush on dst change (~1 per avg-degree edges).
// Packed indices batch-loaded 8-at-a-time, shfl(w=8)-broadcast -> all
// loads in an unrolled batch are independent (deep pipeline). MLP phase
// in-block after one barrier: half-wave per 8 nodes, W in LDS (lane j ->
// bank j, conflict-free), broadcast LDS reads (free).
__global__ void __launch_bounds__(256) gine_fused3_kernel(
    const float* __restrict__ x, const unsigned* __restrict__ eah,
    const int* __restrict__ srcpk, const int* __restrict__ row,
    const float* __restrict__ W1, const float* __restrict__ b1,
    const float* __restrict__ W2, const float* __restrict__ b2,
    const float* __restrict__ eps, int l, float* __restrict__ out, int N)
{
    __shared__ float aggr[NPB][D];          // 8KB
    __shared__ float W1s[D * D], W2s[D * D];
    __shared__ float b1s[D], b2s[D];
    __shared__ float ys[8][D];

    int t = threadIdx.x;
    for (int i = t; i < D * D; i += 256) { W1s[i] = W1[i]; W2s[i] = W2[i]; }
    if (t < D) { b1s[t] = b1[t]; b2s[t] = b2[t]; }
    for (int i = t; i < NPB * D; i += 256) ((float*)aggr)[i] = 0.f;

    int g8 = t >> 3;                        // group 0..31
    int q  = t & 7;                         // lane in group; owns features 4q..4q+3
    int n0 = blockIdx.x * NPB;
    int nlast = min(n0 + NPB - 1, N - 1);
    int estart = n0 ? row[n0 - 1] : 0;      // row[] is inclusive prefix
    int eend   = row[nlast];
    __syncthreads();

    // -------- edge aggregation --------
    int EB = eend - estart;
    int chunk = (EB + 31) >> 5;
    int a = estart + g8 * chunk;
    int b = min(a + chunk, eend);

    float4 acc = make_float4(0.f, 0.f, 0.f, 0.f);
    int cur = -1;
    int k = a;
    while (k + 8 <= b) {
        int pv = srcpk[k + q];              // 8 packed indices, one 32B load
        #pragma unroll
        for (int i = 0; i < 8; ++i) {
            int p  = __shfl(pv, i, 8);
            int s  = p & SRC_MASK;
            int ld = (p >> SRC_BITS) & (NPB - 1);
            uint2 w = *reinterpret_cast<const uint2*>(eah + (size_t)(k + i) * 8 + q);
            float4 xv = *reinterpret_cast<const float4*>(x + (size_t)s * D + q * 4);
            if (ld != cur) {
                if (cur >= 0) {
                    atomicAdd(&aggr[cur][q * 4 + 0], acc.x);
                    atomicAdd(&aggr[cur][q * 4 + 1], acc.y);
                    atomicAdd(&aggr[cur][q * 4 + 2], acc.z);
                    atomicAdd(&aggr[cur][q * 4 + 3], acc.w);
                }
                cur = ld;
                acc = make_float4(0.f, 0.f, 0.f, 0.f);
            }
            acc.x += relu_f(xv.x + __uint_as_float(w.x << 16));
            acc.y += relu_f(xv.y + __uint_as_float(w.x & 0xFFFF0000u));
            acc.z += relu_f(xv.z + __uint_as_float(w.y << 16));
            acc.w += relu_f(xv.w + __uint_as_float(w.y & 0xFFFF0000u));
        }
        k += 8;
    }
    while (k < b) {                          // tail (<8 edges)
        int p  = srcpk[k];                   // same addr across group: broadcast
        int s  = p & SRC_MASK;
        int ld = (p >> SRC_BITS) & (NPB - 1);
        uint2 w = *reinterpret_cast<const uint2*>(eah + (size_t)k * 8 + q);
        float4 xv = *reinterpret_cast<const float4*>(x + (size_t)s * D + q * 4);
        if (ld != cur) {
            if (cur >= 0) {
                atomicAdd(&aggr[cur][q * 4 + 0], acc.x);
                atomicAdd(&aggr[cur][q * 4 + 1], acc.y);
                atomicAdd(&aggr[cur][q * 4 + 2], acc.z);
                atomicAdd(&aggr[cur][q * 4 + 3], acc.w);
            }
            cur = ld;
            acc = make_float4(0.f, 0.f, 0.f, 0.f);
        }
        acc.x += relu_f(xv.x + __uint_as_float(w.x << 16));
        acc.y += relu_f(xv.y + __uint_as_float(w.x & 0xFFFF0000u));
        acc.z += relu_f(xv.z + __uint_as_float(w.y << 16));
        acc.w += relu_f(xv.w + __uint_as_float(w.y & 0xFFFF0000u));
        ++k;
    }
    if (cur >= 0) {
        atomicAdd(&aggr[cur][q * 4 + 0], acc.x);
        atomicAdd(&aggr[cur][q * 4 + 1], acc.y);
        atomicAdd(&aggr[cur][q * 4 + 2], acc.z);
        atomicAdd(&aggr[cur][q * 4 + 3], acc.w);
    }
    __syncthreads();

    // -------- MLP: half-wave hw owns nodes hw*8 .. hw*8+7 --------
    int hw = t >> 5, j = t & 31;
    float ep1 = 1.0f + eps[l];
    for (int r = 0; r < 8; ++r) {
        int ln = hw * 8 + r;
        int n = n0 + ln;
        if (n >= N) break;                  // no barriers below: safe
        float h = ep1 * x[(size_t)n * D + j] + aggr[ln][j];
        aggr[ln][j] = h;                    // stage for broadcast reads
        float a1 = b1s[j];
        #pragma unroll
        for (int kk = 0; kk < D; ++kk)
            a1 = fmaf(aggr[ln][kk], W1s[kk * D + j], a1);
        float y = relu_f(a1);
        ys[hw][j] = y;
        float a2 = b2s[j];
        #pragma unroll
        for (int kk = 0; kk < D; ++kk)
            a2 = fmaf(ys[hw][kk], W2s[kk * D + j], a2);
        out[(size_t)n * D + j] = relu_f(a2);
    }
}

// ================= fallback fused kernel (CSR gather path) =============
__global__ void __launch_bounds__(256) gine_fused_kernel(
    const float* __restrict__ x, const float* __restrict__ ea,
    const int* __restrict__ srcperm, const int* __restrict__ eperm,
    const int* __restrict__ row,
    const float* __restrict__ W1, const float* __restrict__ b1,
    const float* __restrict__ W2, const float* __restrict__ b2,
    const float* __restrict__ eps, int l, float* __restrict__ out, int N)
{
    __shared__ float W1s[D * D], W2s[D * D], b1s[D], b2s[D];
    int t = threadIdx.x;
    for (int i = t; i < D * D; i += 256) { W1s[i] = W1[i]; W2s[i] = W2[i]; }
    if (t < D) { b1s[t] = b1[t]; b2s[t] = b2[t]; }
    __syncthreads();

    int g = t >> 5, j = t & 31;
    int node = blockIdx.x * 8 + g;
    if (node >= N) return;
    int start = node ? row[node - 1] : 0;
    int end = row[node];

    float acc = 0.f;
    for (int k = start; k < end; ++k) {
        int s0 = srcperm[k];
        float e0 = ea[(size_t)eperm[k] * D + j];
        acc += relu_f(x[(size_t)s0 * D + j] + e0);
    }
    float h = (1.0f + eps[l]) * x[(size_t)node * D + j] + acc;
    float a1 = b1s[j];
    #pragma unroll
    for (int kk = 0; kk < D; ++kk)
        a1 = fmaf(__shfl(h, kk, 32), W1s[kk * D + j], a1);
    float y = relu_f(a1);
    float a2 = b2s[j];
    #pragma unroll
    for (int kk = 0; kk < D; ++kk)
        a2 = fmaf(__shfl(y, kk, 32), W2s[kk * D + j], a2);
    out[(size_t)node * D + j] = relu_f(a2);
}

// ===================== atomic fallback path ====================
__global__ void __launch_bounds__(256) gine_scatter_kernel(
    const float* __restrict__ x, const float* __restrict__ ea,
    const int* __restrict__ src, const int* __restrict__ dst,
    float* __restrict__ aggr, int E)
{
    int i = blockIdx.x * blockDim.x + threadIdx.x;
    if (i >= E * 8) return;
    int e = i >> 3, q = i & 7;
    float4 a = reinterpret_cast<const float4*>(ea)[(size_t)e * 8 + q];
    int s = src[e], d = dst[e];
    float4 xv = reinterpret_cast<const float4*>(x)[(size_t)s * 8 + q];
    float* base = aggr + (size_t)d * D + (size_t)q * 4;
    __hip_atomic_fetch_add(base + 0, relu_f(xv.x + a.x), __ATOMIC_RELAXED, __HIP_MEMORY_SCOPE_AGENT);
    __hip_atomic_fetch_add(base + 1, relu_f(xv.y + a.y), __ATOMIC_RELAXED, __HIP_MEMORY_SCOPE_AGENT);
    __hip_atomic_fetch_add(base + 2, relu_f(xv.z + a.z), __ATOMIC_RELAXED, __HIP_MEMORY_SCOPE_AGENT);
    __hip_atomic_fetch_add(base + 3, relu_f(xv.w + a.w), __ATOMIC_RELAXED, __HIP_MEMORY_SCOPE_AGENT);
}

__global__ void __launch_bounds__(256) gine_node_kernel(
    const float* __restrict__ x, const float* __restrict__ aggr,
    const float* __restrict__ W1, const float* __restrict__ b1,
    const float* __restrict__ W2, const float* __restrict__ b2,
    const float* __restrict__ eps, int l, float* __restrict__ out, int N)
{
    __shared__ float W1s[D * D], W2s[D * D], b1s[D], b2s[D];
    __shared__ float hs[8][D], y1s[8][D];
    int t = threadIdx.x;
    for (int i = t; i < D * D; i += 256) { W1s[i] = W1[i]; W2s[i] = W2[i]; }
    if (t < D) { b1s[t] = b1[t]; b2s[t] = b2[t]; }
    float ep1 = 1.0f + eps[l];
    int local = t >> 5, j = t & 31;
    int node = blockIdx.x * 8 + local;
    __syncthreads();
    if (node < N)
        hs[local][j] = ep1 * x[(size_t)node * D + j] + aggr[(size_t)node * D + j];
    __syncthreads();
    if (node < N) {
        float acc = b1s[j];
        #pragma unroll
        for (int k = 0; k < D; ++k) acc = fmaf(hs[local][k], W1s[k * D + j], acc);
        y1s[local][j] = relu_f(acc);
    }
    __syncthreads();
    if (node < N) {
        float acc = b2s[j];
        #pragma unroll
        for (int k = 0; k < D; ++k) acc = fmaf(y1s[local][k], W2s[k * D + j], acc);
        out[(size_t)node * D + j] = relu_f(acc);
    }
}

// ============================== launcher ===============================
extern "C" void kernel_launch(void* const* d_in, const int* in_sizes, int n_in,
                              void* d_out, int out_size, void* d_ws, size_t ws_size,
                              hipStream_t stream) {
    const float* x_in = (const float*)d_in[0];
    const float* ea   = (const float*)d_in[1];
    const int*   ei   = (const int*)d_in[2];
    const float* W1   = (const float*)d_in[3];
    const float* b1   = (const float*)d_in[4];
    const float* W2   = (const float*)d_in[5];
    const float* b2   = (const float*)d_in[6];
    const float* eps  = (const float*)d_in[7];

    int N = in_sizes[0] / D;
    int E = in_sizes[1] / D;
    int L = in_sizes[3] / (D * D);

    const int* src = ei;       // edge_index[0] = message source j
    const int* dst = ei + E;   // edge_index[1] = message target i

    float* out = (float*)d_out;
    char*  ws  = (char*)d_ws;

    size_t off = 0;
    auto take = [&](size_t bytes) -> size_t {
        size_t p = off; off = (off + bytes + 255) & ~(size_t)255; return p;
    };
    size_t o_bufA    = take((size_t)N * D * sizeof(float));
    size_t o_row     = take((size_t)(N + 8) * sizeof(int));
    size_t o_part    = take(1024 * sizeof(int));
    size_t o_srcpk   = take((size_t)E * sizeof(int));
    size_t base_need = off;
    size_t o_eperm   = base_need;                          // CSR path
    size_t need_csr  = base_need + (((size_t)E * sizeof(int) + 255) & ~(size_t)255);
    size_t o_eah     = base_need;                          // FULL path (bf16)
    size_t need_full = base_need + (size_t)E * D * sizeof(unsigned short);

    float* bufA  = (float*)(ws + o_bufA);
    int*   row   = (int*)(ws + o_row);
    int*   part  = (int*)(ws + o_part);
    int*   srcpk = (int*)(ws + o_srcpk);

    int path = (ws_size >= need_full) ? 2 : (ws_size >= need_csr ? 1 : 0);

    if (path == 0) {
        float* aggr = bufA + (size_t)N * D;   // legacy path (needs 2*N*D)
        const float* cur = x_in;
        for (int l = 0; l < L; ++l) {
            float* nxt = (((L - 1 - l) & 1) == 0) ? out : bufA;
            hipMemsetAsync(aggr, 0, (size_t)N * D * sizeof(float), stream);
            gine_scatter_kernel<<<(E * 8 + 255) / 256, 256, 0, stream>>>(cur, ea, src, dst, aggr, E);
            gine_node_kernel<<<(N + 7) / 8, 256, 0, stream>>>(
                cur, aggr, W1 + (size_t)l * D * D, b1 + (size_t)l * D,
                W2 + (size_t)l * D * D, b2 + (size_t)l * D, eps, l, nxt, N);
            cur = nxt;
        }
        return;
    }

    int*      eperm = (int*)(ws + o_eperm);
    unsigned* eah   = (unsigned*)(ws + o_eah);

    // ---- preprocessing (once per call) ----
    int nb = (N + SCAN_CHUNK - 1) / SCAN_CHUNK;
    hipMemsetAsync(row, 0, (size_t)N * sizeof(int), stream);
    hist_kernel<<<(E + 255) / 256, 256, 0, stream>>>(dst, row, E);
    scan_partial_kernel<<<nb, 256, 0, stream>>>(row, part, N);
    scan_part_exclusive_kernel<<<1, 64, 0, stream>>>(part, nb);
    scan_final_kernel<<<nb, 256, 0, stream>>>(row, part, N);
    if (path == 2) {
        place_full_kernel<<<(E * 8 + 255) / 256, 256, 0, stream>>>(
            src, dst, ea, row, srcpk, eah, E);
    } else {
        place_csr_kernel<<<(E + 255) / 256, 256, 0, stream>>>(
            src, dst, row, srcpk, eperm, E);
    }
    // row[n] is now the inclusive prefix (end offset of node n)

    const float* cur = x_in;
    for (int l = 0; l < L; ++l) {
        float* nxt = (((L - 1 - l) & 1) == 0) ? out : bufA;
        if (path == 2) {
            gine_fused3_kernel<<<(N + NPB - 1) / NPB, 256, 0, stream>>>(
                cur, eah, srcpk, row,
                W1 + (size_t)l * D * D, b1 + (size_t)l * D,
                W2 + (size_t)l * D * D, b2 + (size_t)l * D, eps, l, nxt, N);
        } else {
            gine_fused_kernel<<<(N + 7) / 8, 256, 0, stream>>>(
                cur, ea, srcpk, eperm, row,
                W1 + (size_t)l * D * D, b1 + (size_t)l * D,
                W2 + (size_t)l * D * D, b2 + (size_t)l * D, eps, l, nxt, N);
        }
        cur = nxt;
    }
}